// Round 9
// baseline (163.502 us; speedup 1.0000x reference)
//
#include <hip/hip_runtime.h>
#include <stdint.h>

#define L_SEQ 2048
#define BATCH 2
#define DMODEL 512
#define PROJ 1024
#define NST 32
#define NCATU 1088  // 1024 (Wd) + 32 (WB) + 32 (WC) -> 17*64
#define ROWS (BATCH*L_SEQ)  // 4096
#define THRESH 50.0f        // suffix cutoff (nats)

typedef float f32x4 __attribute__((ext_vector_type(4)));
typedef short short8 __attribute__((ext_vector_type(8)));

__device__ inline float bf2f(unsigned short u){ uint32_t x=((uint32_t)u)<<16; float f; __builtin_memcpy(&f,&x,4); return f; }
__device__ inline unsigned short f2bf(float f){ uint32_t x; __builtin_memcpy(&x,&f,4); uint32_t r=x+0x7FFFu+((x>>16)&1u); return (unsigned short)(r>>16); }
__device__ inline float siluf(float x){ return x/(1.f+__expf(-x)); }
__device__ inline float softplusf(float x){ return x>20.f? x : log1pf(__expf(x)); }

#define AS1(p) ((const __attribute__((address_space(1))) void*)(p))
#define AS3(p) ((__attribute__((address_space(3))) void*)(p))

template<int N> __device__ inline void wait_vmcnt(){
  if constexpr (N==0)      asm volatile("s_waitcnt vmcnt(0)" ::: "memory");
  else if constexpr (N==2) asm volatile("s_waitcnt vmcnt(2)" ::: "memory");
  else                     asm volatile("s_waitcnt vmcnt(4)" ::: "memory");
}

// ---------------- weight prep: fp32 -> bf16 transposed / concatenated ----------------
__global__ __launch_bounds__(256)
void prep_kernel(const float* __restrict__ W1, const float* __restrict__ b1,
                 const float* __restrict__ W2, const float* __restrict__ b2,
                 const float* __restrict__ Wd, const float* __restrict__ bd,
                 const float* __restrict__ WB, const float* __restrict__ bB,
                 const float* __restrict__ WC, const float* __restrict__ bC,
                 const float* __restrict__ W3,
                 unsigned short* __restrict__ W12t, unsigned short* __restrict__ Wcatt,
                 unsigned short* __restrict__ W3t, float* __restrict__ bias12,
                 float* __restrict__ biascat)
{
  int i = blockIdx.x*256 + threadIdx.x;
  const int nA = 2048*512;        // W12t [2048][512]
  const int nB = NCATU*1024;      // Wcatt [1088][1024]
  const int nC = 512*1024;        // W3t  [512][1024]
  if (i < nA) {
    int n = i >> 9, k = i & 511;
    float v = (n < 1024) ? W1[k*1024 + n] : W2[k*1024 + (n-1024)];
    W12t[i] = f2bf(v);
    return;
  }
  i -= nA;
  if (i < nB) {
    int n = i >> 10, k = i & 1023;
    float v;
    if (n < 1024) v = Wd[k*1024 + n];
    else if (n < 1056) v = WB[k*32 + (n-1024)];
    else v = WC[k*32 + (n-1056)];
    Wcatt[i] = f2bf(v);
    return;
  }
  i -= nB;
  if (i < nC) {
    int n = i >> 10, k = i & 1023;
    W3t[i] = f2bf(W3[k*512 + n]);
    return;
  }
  i -= nC;
  if (i < 2048) { bias12[i] = (i < 1024) ? b1[i] : b2[i-1024]; return; }
  i -= 2048;
  if (i < NCATU) {
    biascat[i] = (i < 1024) ? bd[i] : (i < 1056) ? bB[i-1024] : bC[i-1056];
  }
}

// ---------------- LayerNorm: one wave per row of 512, write bf16 ----------------
__global__ __launch_bounds__(256)
void ln_kernel(const float* __restrict__ x, const float* __restrict__ gamma,
               const float* __restrict__ beta, unsigned short* __restrict__ H)
{
  int row = blockIdx.x*4 + (threadIdx.x >> 6);
  int lane = threadIdx.x & 63;
  const float4* xr = (const float4*)(x + (size_t)row*DMODEL);
  float4 v0 = xr[lane];
  float4 v1 = xr[lane+64];
  float s = v0.x+v0.y+v0.z+v0.w + v1.x+v1.y+v1.z+v1.w;
  float q = v0.x*v0.x+v0.y*v0.y+v0.z*v0.z+v0.w*v0.w
          + v1.x*v1.x+v1.y*v1.y+v1.z*v1.z+v1.w*v1.w;
#pragma unroll
  for (int m=32;m>0;m>>=1){ s += __shfl_xor(s,m); q += __shfl_xor(q,m); }
  float mu = s*(1.f/DMODEL);
  float var = q*(1.f/DMODEL) - mu*mu;
  float rs = rsqrtf(var + 1e-3f);
  int c0 = lane*4, c1 = 256 + lane*4;
  float4 g0 = *(const float4*)&gamma[c0]; float4 g1 = *(const float4*)&gamma[c1];
  float4 t0 = *(const float4*)&beta[c0];  float4 t1 = *(const float4*)&beta[c1];
  ushort4 o0, o1;
  o0.x = f2bf((v0.x-mu)*rs*g0.x + t0.x);
  o0.y = f2bf((v0.y-mu)*rs*g0.y + t0.y);
  o0.z = f2bf((v0.z-mu)*rs*g0.z + t0.z);
  o0.w = f2bf((v0.w-mu)*rs*g0.w + t0.w);
  o1.x = f2bf((v1.x-mu)*rs*g1.x + t1.x);
  o1.y = f2bf((v1.y-mu)*rs*g1.y + t1.y);
  o1.z = f2bf((v1.z-mu)*rs*g1.z + t1.z);
  o1.w = f2bf((v1.w-mu)*rs*g1.w + t1.w);
  *(ushort4*)&H[(size_t)row*DMODEL + c0] = o0;
  *(ushort4*)&H[(size_t)row*DMODEL + c1] = o1;
}

// ---------------- weights-resident GEMM ----------------
// Block = 4 waves; wave owns 16 out-cols; weights for those cols (16 x KD) live in
// VGPRs (loaded once). Only the 64-token x 64-K activation tile is staged per k-step
// (8 KB -> AI=64 FLOP/B through the gload_lds path, 2x the old both-operands scheme).
// K-loop fully unrolled so breg[] indexing is compile-time (rule #20).
// MODE 1: P12 bf16 [4096][2048], +bias[c].
// MODE 2: CT fp32 [NCATU][4096], +bias[c], softplus c<1024 (float4 writes).
// MODE 3: d_out fp32 [4096][512], +bias[c] +res.
template<int KD, int TT, int MODE>
__global__ __launch_bounds__(256)
void wgemm(const unsigned short* __restrict__ W, const unsigned short* __restrict__ Act,
           void* __restrict__ out, const float* __restrict__ bias,
           const float* __restrict__ res)
{
  constexpr int T = KD/64;            // k-steps per token-tile
  __shared__ unsigned short As[3][64*64];   // 3 x 8 KB
  int tid = threadIdx.x;
  int lane = tid & 63, wid = tid >> 6;
  int r = lane & 15, kb = lane >> 4;
  int c = blockIdx.x*64 + wid*16 + r;       // this lane's out col = weight row

  // resident weight fragments: breg[kc] covers k = kc*32 + kb*8 .. +8
  short8 breg[KD/32];
#pragma unroll
  for (int kc=0; kc<KD/32; ++kc)
    breg[kc] = *(const short8*)&W[(size_t)c*KD + kc*32 + kb*8];

  for (int tt=0; tt<TT; ++tt) {
    int tok0 = (blockIdx.y*TT + tt)*64;
    const unsigned short* ap[2];
#pragma unroll
    for (int j=0;j<2;j++){
      int s = tid + j*256;
      int row = s >> 3, kc = ((s & 7) ^ (row & 7)) * 8;  // XOR swizzle on source
      ap[j] = Act + (size_t)(tok0+row)*KD + kc;
    }
    auto stage = [&](int buf){
#pragma unroll
      for (int j=0;j<2;j++){
        __builtin_amdgcn_global_load_lds(AS1(ap[j]), AS3(&As[buf][(size_t)(j*256 + wid*64)*8]), 16, 0, 0);
        ap[j] += 64;
      }
    };
    stage(0);
    if (T > 1) stage(1);

    f32x4 acc[4];
#pragma unroll
    for (int i=0;i<4;i++)
#pragma unroll
      for (int e=0;e<4;e++) acc[i][e] = 0.f;

#pragma unroll
    for (int t=0; t<T; ++t) {
      if (t+1 < T) wait_vmcnt<2>();   // stage(t) landed; stage(t+1) in flight
      else         wait_vmcnt<0>();
      __builtin_amdgcn_s_barrier();
      if (t+2 < T) stage((t+2)%3);
#pragma unroll
      for (int ks=0; ks<2; ++ks) {
        short8 af[4];
#pragma unroll
        for (int i=0;i<4;i++){
          int row = i*16 + r;
          int cx = (ks*4 + kb) ^ (r & 7);  // swizzled read
          af[i] = *(const short8*)&As[t%3][(row*8 + cx)*8];
        }
#pragma unroll
        for (int i=0;i<4;i++)
          acc[i] = __builtin_amdgcn_mfma_f32_16x16x32_bf16(af[i], breg[t*2+ks], acc[i], 0,0,0);
      }
    }

    int rr = kb*4;
    float bv = bias[c];
    if constexpr (MODE == 1) {
#pragma unroll
      for (int i=0;i<4;i++)
#pragma unroll
        for (int e=0;e<4;e++)
          ((unsigned short*)out)[(size_t)(tok0 + i*16 + rr + e)*2048 + c] = f2bf(acc[i][e] + bv);
    } else if constexpr (MODE == 2) {
#pragma unroll
      for (int i=0;i<4;i++){
        float4 o;
        float v0 = acc[i][0] + bv, v1 = acc[i][1] + bv, v2 = acc[i][2] + bv, v3 = acc[i][3] + bv;
        if (c < 1024) { v0 = softplusf(v0); v1 = softplusf(v1); v2 = softplusf(v2); v3 = softplusf(v3); }
        o.x = v0; o.y = v1; o.z = v2; o.w = v3;
        *(float4*)&((float*)out)[(size_t)c*ROWS + tok0 + i*16 + rr] = o;
      }
    } else {
#pragma unroll
      for (int i=0;i<4;i++)
#pragma unroll
        for (int e=0;e<4;e++){
          int row = tok0 + i*16 + rr + e;
          ((float*)out)[(size_t)row*512 + c] = acc[i][e] + bv + res[(size_t)row*512 + c];
        }
    }
    __syncthreads();   // guard As reuse before next tile's stage
  }
}

// ---------------- causal depthwise conv (K=4) + SiLU; also SiLU for x2 (bf16 in) ----------------
__global__ __launch_bounds__(256)
void conv_silu_kernel(const unsigned short* __restrict__ P12, const float* __restrict__ ck,
                      const float* __restrict__ cb, unsigned short* __restrict__ ubf,
                      unsigned short* __restrict__ x2bf)
{
  int gid = blockIdx.x*256 + threadIdx.x;   // ROWS * 512 tasks
  int c4 = gid & 511;
  int row = gid >> 9;
  int l = row & (L_SEQ-1);
  if (c4 < 256) {
    int c = c4*4;
    float4 bv = *(const float4*)&cb[c];
    float r0=bv.x, r1=bv.y, r2=bv.z, r3=bv.w;
#pragma unroll
    for (int t=0;t<4;t++){
      int lsrc = l - 3 + t;
      if (lsrc >= 0) {
        ushort4 xv = *(const ushort4*)&P12[(size_t)(row-3+t)*2048 + c];
        float4 kv = *(const float4*)&ck[t*PROJ + c];
        r0 = fmaf(bf2f(xv.x),kv.x,r0);
        r1 = fmaf(bf2f(xv.y),kv.y,r1);
        r2 = fmaf(bf2f(xv.z),kv.z,r2);
        r3 = fmaf(bf2f(xv.w),kv.w,r3);
      }
    }
    ushort4 o;
    o.x=f2bf(siluf(r0)); o.y=f2bf(siluf(r1)); o.z=f2bf(siluf(r2)); o.w=f2bf(siluf(r3));
    *(ushort4*)&ubf[(size_t)row*PROJ + c] = o;
  } else {
    int c = (c4-256)*4;
    ushort4 xv = *(const ushort4*)&P12[(size_t)row*2048 + 1024 + c];
    ushort4 o;
    o.x=f2bf(siluf(bf2f(xv.x))); o.y=f2bf(siluf(bf2f(xv.y)));
    o.z=f2bf(siluf(bf2f(xv.z))); o.w=f2bf(siluf(bf2f(xv.w)));
    *(ushort4*)&x2bf[(size_t)row*PROJ + c] = o;
  }
}

// ---------------- per-(b,d): 8-boundary suffix sums + l0, reading CT row d ----------------
__global__ __launch_bounds__(256)
void tsum_kernel(const float* __restrict__ CT, float* __restrict__ suf8,
                 int* __restrict__ l0out)
{
  int G = blockIdx.x;              // b*1024 + d
  int b = G >> 10, d = G & 1023;
  const float* row = CT + (size_t)d*ROWS + b*L_SEQ;
  int t = threadIdx.x;
  float4 v0 = *(const float4*)&row[t*8];
  float4 v1 = *(const float4*)&row[t*8+4];
  float vals[8] = {v0.x,v0.y,v0.z,v0.w,v1.x,v1.y,v1.z,v1.w};
  float part = 0.f;
#pragma unroll
  for (int i=0;i<8;i++) part += vals[i];
  __shared__ float ps[256];
  ps[t] = part; __syncthreads();
  for (int off=1; off<256; off<<=1){
    float v = (t >= off) ? ps[t-off] : 0.f;
    __syncthreads();
    ps[t] += v;
    __syncthreads();
  }
  float T = ps[255];
  float prefx = ps[t] - part;      // exclusive prefix of this thread's 8-chunk
  suf8[(size_t)G*(L_SEQ/8) + t] = T - prefx;   // suffix incl. position 8t
  float run = prefx; int cnt = 0;
#pragma unroll
  for (int i=0;i<8;i++){
    float suf_l = T - run;
    cnt += (suf_l >= THRESH) ? 1 : 0;
    run += vals[i];
  }
  __shared__ int cs[256];
  cs[t] = cnt; __syncthreads();
  for (int off=128; off>0; off>>=1){ if (t < off) cs[t] += cs[t+off]; __syncthreads(); }
  if (t == 0) {
    int total = cs[0];
    l0out[G] = total > 0 ? total-1 : 0;
  }
}

// ---------------- windowed gated selective scan: contiguous delta/B/C from CT ----------------
__global__ __launch_bounds__(256)
void scan_kernel(const float* __restrict__ CT, const float* __restrict__ suf8,
                 const unsigned short* __restrict__ ubf, const float* __restrict__ A_log,
                 const int* __restrict__ l0arr, float* __restrict__ ystate)
{
  int tid = threadIdx.x;
  int n = tid & 31;
  int G = blockIdx.x*8 + (tid >> 5);
  int b = G >> 10, d = G & 1023;
  float np1 = __expf(A_log[d*NST + n]);   // -A[d,n] = n+1
  int myl0 = l0arr[G];
  int base = min(myl0, __shfl_xor(myl0, 32)) & ~7;   // wave-uniform, 8-aligned
  const float* dT = CT + (size_t)d*ROWS + b*L_SEQ;           // softplus'd delta
  const float* Br = CT + (size_t)(1024+n)*ROWS + b*L_SEQ;
  const float* Cr = CT + (size_t)(1056+n)*ROWS + b*L_SEQ;
  const float* s8 = suf8 + (size_t)G*(L_SEQ/8);
  const unsigned short* ub = ubf + (size_t)b*L_SEQ*PROJ + d;
  float* yb = ystate + (size_t)b*L_SEQ*PROJ + d;
  float s = 0.f;
  for (int l = base; l < L_SEQ; l += 8) {
    float4 d0 = *(const float4*)&dT[l];
    float4 d1 = *(const float4*)&dT[l+4];
    float4 B0 = *(const float4*)&Br[l];
    float4 B1 = *(const float4*)&Br[l+4];
    float4 C0 = *(const float4*)&Cr[l];
    float4 C1 = *(const float4*)&Cr[l+4];
    float sufv = s8[l >> 3];                 // suffix incl. position l
    float dl[8] = {d0.x,d0.y,d0.z,d0.w,d1.x,d1.y,d1.z,d1.w};
    float Bv[8] = {B0.x,B0.y,B0.z,B0.w,B1.x,B1.y,B1.z,B1.w};
    float Cv[8] = {C0.x,C0.y,C0.z,C0.w,C1.x,C1.y,C1.z,C1.w};
    float uu[8];
#pragma unroll
    for (int t=0;t<8;t++) uu[t] = bf2f(ub[(size_t)(l+t)*PROJ]);
    float cum = 0.f;
#pragma unroll
    for (int t=0;t<8;t++){
      cum += dl[t];
      float decay = __expf(-dl[t]*np1);
      s = fmaf(decay, s, dl[t]*uu[t]*Bv[t]);
      float gte = 1.f/(1.f + 1e-12f*__expf(np1*(sufv - cum)));  // overflow->inf->0
      float contrib = s*gte*Cv[t];
#pragma unroll
      for (int m=16;m>0;m>>=1) contrib += __shfl_xor(contrib, m);
      if (n == 0) yb[(size_t)(l+t)*PROJ] = contrib;
    }
  }
}

// ---------------- z = (ystate_gated + u*D_skip) * x2 -> bf16 (l0-gated, no memset) ----------------
__global__ __launch_bounds__(256)
void zmul_kernel(const float* __restrict__ ystate, const unsigned short* __restrict__ ubf,
                 const unsigned short* __restrict__ x2bf, const float* __restrict__ Dskip,
                 const int* __restrict__ l0arr, unsigned short* __restrict__ zbf)
{
  size_t i = ((size_t)blockIdx.x*256 + threadIdx.x)*4;
  int d = (int)(i & (PROJ-1));
  int row = (int)(i >> 10);
  int l = row & (L_SEQ-1);
  int b = row >> 11;
  int4 l0v = *(const int4*)&l0arr[b*PROJ + d];
  float4 ys = *(const float4*)&ystate[i];
  ys.x = (l >= l0v.x) ? ys.x : 0.f;
  ys.y = (l >= l0v.y) ? ys.y : 0.f;
  ys.z = (l >= l0v.z) ? ys.z : 0.f;
  ys.w = (l >= l0v.w) ? ys.w : 0.f;
  ushort4 uu = *(const ushort4*)&ubf[i];
  ushort4 xx = *(const ushort4*)&x2bf[i];
  float4 Dv = *(const float4*)&Dskip[d];
  ushort4 o;
  o.x = f2bf((ys.x + bf2f(uu.x)*Dv.x)*bf2f(xx.x));
  o.y = f2bf((ys.y + bf2f(uu.y)*Dv.y)*bf2f(xx.y));
  o.z = f2bf((ys.z + bf2f(uu.z)*Dv.z)*bf2f(xx.z));
  o.w = f2bf((ys.w + bf2f(uu.w)*Dv.w)*bf2f(xx.w));
  *(ushort4*)&zbf[i] = o;
}

extern "C" void kernel_launch(void* const* d_in, const int* in_sizes, int n_in,
                              void* d_out, int out_size, void* d_ws, size_t ws_size,
                              hipStream_t stream)
{
  const float* x     = (const float*)d_in[0];
  const float* ln_g  = (const float*)d_in[1];
  const float* ln_b  = (const float*)d_in[2];
  const float* W1    = (const float*)d_in[3];
  const float* b1    = (const float*)d_in[4];
  const float* W2    = (const float*)d_in[5];
  const float* b2    = (const float*)d_in[6];
  const float* convk = (const float*)d_in[7];
  const float* convb = (const float*)d_in[8];
  const float* A_log = (const float*)d_in[9];
  const float* Dskip = (const float*)d_in[10];
  const float* WB    = (const float*)d_in[11];
  const float* bB    = (const float*)d_in[12];
  const float* WC    = (const float*)d_in[13];
  const float* bC    = (const float*)d_in[14];
  const float* Wd    = (const float*)d_in[15];
  const float* bd    = (const float*)d_in[16];
  const float* W3    = (const float*)d_in[17];
  const float* b3    = (const float*)d_in[18];

  char* w = (char*)d_ws;
  auto alloc = [&](size_t bytes){ char* p = w; w += (bytes + 255) & ~(size_t)255; return p; };
  unsigned short* Hbf    = (unsigned short*)alloc((size_t)ROWS*DMODEL*2);
  unsigned short* W12t   = (unsigned short*)alloc((size_t)2048*512*2);
  unsigned short* Wcatt  = (unsigned short*)alloc((size_t)NCATU*1024*2);
  unsigned short* W3t    = (unsigned short*)alloc((size_t)512*1024*2);
  float*          bias12 = (float*)alloc(2048*4);
  float*          biascat= (float*)alloc(NCATU*4);
  unsigned short* P12    = (unsigned short*)alloc((size_t)ROWS*2048*2);
  unsigned short* ubf    = (unsigned short*)alloc((size_t)ROWS*PROJ*2);
  unsigned short* x2bf   = (unsigned short*)alloc((size_t)ROWS*PROJ*2);
  float*          CT     = (float*)alloc((size_t)NCATU*ROWS*4);   // transposed gemm2 out
  float*          suf8   = (float*)alloc((size_t)2048*(L_SEQ/8)*4);
  int*            l0arr  = (int*)alloc(2048*4);
  float*          ystate = (float*)alloc((size_t)ROWS*PROJ*4);
  unsigned short* zbf    = (unsigned short*)alloc((size_t)ROWS*PROJ*2);

  {
    int total = 2048*512 + NCATU*1024 + 512*1024 + 2048 + NCATU;
    prep_kernel<<<(total+255)/256, 256, 0, stream>>>(W1,b1,W2,b2,Wd,bd,WB,bB,WC,bC,W3,
                                                     W12t,Wcatt,W3t,bias12,biascat);
  }
  ln_kernel<<<ROWS/4, 256, 0, stream>>>(x, ln_g, ln_b, Hbf);

  // gemm1: P12[4096][2048] = Hbf x W12t^T   (32 stripes x 32 token-splits, TT=2)
  wgemm<512,2,1><<<dim3(2048/64, 32), 256, 0, stream>>>(W12t, Hbf, P12, bias12, nullptr);

  conv_silu_kernel<<<ROWS*512/256, 256, 0, stream>>>(P12, convk, convb, ubf, x2bf);

  // gemm2 (transposed out): CT[1088][4096] = Wcatt x ubf^T
  wgemm<1024,2,2><<<dim3(NCATU/64, 32), 256, 0, stream>>>(Wcatt, ubf, CT, biascat, nullptr);

  tsum_kernel<<<2048, 256, 0, stream>>>(CT, suf8, l0arr);

  scan_kernel<<<2048/8, 256, 0, stream>>>(CT, suf8, ubf, A_log, l0arr, ystate);

  zmul_kernel<<<(ROWS*PROJ/4)/256, 256, 0, stream>>>(ystate, ubf, x2bf, Dskip, l0arr, zbf);

  // gemm3: out[4096][512] = zbf x W3t^T + x
  wgemm<1024,2,3><<<dim3(512/64, 32), 256, 0, stream>>>(W3t, zbf, (float*)d_out, b3, x);
}